// Round 3
// baseline (535.338 us; speedup 1.0000x reference)
//
#include <hip/hip_runtime.h>
#include <cstdint>
#include <cstddef>

namespace {
constexpr int NN     = 8192;
constexpr int DD     = 32;
constexpr int ROWS   = 128;          // rows per attention block (4 waves x 32)
constexpr int TJ     = 64;           // j-tile (two K=32 MFMA rounds)
constexpr int JSPLIT = 16;           // j-range splits -> 1024 blocks (4/CU)
constexpr int JRANGE = NN / JSPLIT;  // 512
constexpr int WORDS  = NN / 64;      // 128 mask words per row
constexpr int STR    = 72;           // LDS row stride in halfwords (144 B)
}

typedef __attribute__((ext_vector_type(8))) short short8;
typedef __attribute__((ext_vector_type(4))) float floatx4;

__device__ __forceinline__ unsigned short f2bf(float f) {
  unsigned int u = __float_as_uint(f);
  u += 0x7fffu + ((u >> 16) & 1u);          // RNE
  return (unsigned short)(u >> 16);
}

// ---------------------------------------------------------------------------
// g = in @ W (optionally in = ELU(acc/den)); s_src = g@a[:D]; s_dst = g@a[D:]
// W cached in LDS. Outputs: fp32 g (layer 3) and/or bf16 transposed
// gT[d][node] (layers 1/2; coalesced in node; L2-resident for k_att B-frags).
// ---------------------------------------------------------------------------
template<int DIN, int DOUT, bool FROMACC>
__global__ void k_g(const float* __restrict__ in,
                    const float* __restrict__ den,
                    const float* __restrict__ W,
                    const float* __restrict__ avec,
                    float* __restrict__ g,
                    unsigned short* __restrict__ gT,
                    float* __restrict__ ssrc,
                    float* __restrict__ sdst)
{
  __shared__ float Ws[DIN * DOUT];
  __shared__ float as[2 * DOUT];
  const int t = threadIdx.x;  // 128
  for (int idx = t; idx < DIN * DOUT; idx += 128) Ws[idx] = W[idx];
  if (t < 2 * DOUT) as[t] = avec[t];
  __syncthreads();

  const int i = blockIdx.x * 128 + t;
  float h[DIN];
  if (FROMACC) {
    const float dinv = 1.0f / den[i];
    #pragma unroll
    for (int k = 0; k < DIN; k++) {
      const float v = in[(size_t)i * DIN + k] * dinv;
      h[k] = v > 0.f ? v : (__expf(v) - 1.0f);      // ELU
    }
  } else {
    #pragma unroll
    for (int k = 0; k < DIN; k++) h[k] = in[(size_t)i * DIN + k];
  }
  float ss = 0.f, sd = 0.f;
  #pragma unroll 4
  for (int d = 0; d < DOUT; d++) {
    float a = 0.f;
    #pragma unroll
    for (int k = 0; k < DIN; k++) a += h[k] * Ws[k * DOUT + d];
    if (g)  g[(size_t)i * DOUT + d] = a;
    if (gT) gT[(size_t)d * NN + i] = f2bf(a);       // coalesced in i
    ss += a * as[d];
    sd += a * as[DOUT + d];
  }
  ssrc[i] = ss;
  sdst[i] = sd;
}

// ---------------------------------------------------------------------------
// Attention layer (D=32), bf16 MFMA, BARRIER-FREE: each wave owns 32 rows,
// writes its private wt region (same-wave LDS RAW ordered by compiler), and
// loads B-fragments directly from global gT (L1/L2-resident, 16B/lane in
// MFMA B-layout). No __syncthreads anywhere -> waves free-run, adj latency
// hidden by 4-wave TLP per SIMD. Denominator via ones-B MFMA (identical bf16
// weights in num & den -> w rounding cancels).
// ---------------------------------------------------------------------------
template<int LAYER>
__global__ __launch_bounds__(256, 4)
void k_att(const float* __restrict__ adj,
           unsigned long long* __restrict__ mask64,
           const unsigned short* __restrict__ gT,
           const float* __restrict__ ssrc,
           const float* __restrict__ sdst,
           float* __restrict__ hacc,
           float* __restrict__ den)
{
  __shared__ unsigned short wt[4][32 * STR];   // per-wave private, 18 KB total

  const int t    = threadIdx.x;
  const int lane = t & 63;
  const int wv   = __builtin_amdgcn_readfirstlane(t >> 6);
  const int quad = lane >> 4;
  const int m16  = lane & 15;
  const int rb   = (blockIdx.x / JSPLIT) * ROWS;
  const int j0   = (blockIdx.x % JSPLIT) * JRANGE;
  const int r0   = wv * 32;                    // this wave's 32 rows
  unsigned short* wtw = wt[wv];

  floatx4 acc[2][2];
  floatx4 dacc[2];
  #pragma unroll
  for (int a = 0; a < 2; a++) {
    dacc[a] = (floatx4){0.f, 0.f, 0.f, 0.f};
    #pragma unroll
    for (int b = 0; b < 2; b++) acc[a][b] = (floatx4){0.f, 0.f, 0.f, 0.f};
  }
  short8 ones;
  #pragma unroll
  for (int k = 0; k < 8; k++) ones[k] = (short)0x3F80;  // bf16 1.0

  // B-fragment base pointers: B[k=quad*8+i][n=m16(+16)] = gT[n][j], 16B/lane
  const unsigned short* gb0 = gT + (size_t)m16 * NN + quad * 8;
  const unsigned short* gb1 = gT + (size_t)(16 + m16) * NN + quad * 8;

  for (int jt = j0; jt < j0 + JRANGE; jt += TJ) {
    // issue all global loads up front (latency overlaps phase A compute)
    const short8 b00 = *reinterpret_cast<const short8*>(gb0 + jt);       // ks=0, n 0-15
    const short8 b01 = *reinterpret_cast<const short8*>(gb0 + jt + 32);  // ks=1, n 0-15
    const short8 b10 = *reinterpret_cast<const short8*>(gb1 + jt);       // ks=0, n 16-31
    const short8 b11 = *reinterpret_cast<const short8*>(gb1 + jt + 32);  // ks=1, n 16-31
    const float sdj = sdst[jt + lane];

    // ---- phase A: w for this wave's 32 rows x 64 j (lane = j) ----
    if constexpr (LAYER == 1) {
      float av[32];
      #pragma unroll
      for (int ii = 0; ii < 32; ii++)
        av[ii] = adj[(size_t)(rb + r0 + ii) * NN + jt + lane];   // 256B/wave coalesced
      #pragma unroll
      for (int ii = 0; ii < 32; ii++) {
        const int iu = rb + r0 + ii;
        const float sa = ssrc[iu];                               // uniform -> s_load
        const bool m = av[ii] > 0.5f;
        const unsigned long long bal = __ballot(m);
        if (lane == 0) mask64[(size_t)iu * WORDS + (jt >> 6)] = bal;
        const float e = sa + sdj;
        const float w = m ? __expf(fmaxf(e, 0.2f * e)) : 0.f;
        wtw[ii * STR + lane] = f2bf(w);                          // 2-way = free
      }
    } else {
      #pragma unroll
      for (int ii = 0; ii < 32; ii++) {
        const int iu = rb + r0 + ii;
        const float sa = ssrc[iu];
        const unsigned long long mw = mask64[(size_t)iu * WORDS + (jt >> 6)]; // uniform
        const bool m = (mw >> lane) & 1ull;
        const float e = sa + sdj;
        const float w = m ? __expf(fmaxf(e, 0.2f * e)) : 0.f;
        wtw[ii * STR + lane] = f2bf(w);
      }
    }

    // ---- phase B: A-frags from own wt rows; MFMA (compiler orders lgkmcnt) ----
    #pragma unroll
    for (int ks = 0; ks < 2; ks++) {
      const int ko = ks * 32 + quad * 8;
      const short8 bA = ks ? b01 : b00;
      const short8 bB = ks ? b11 : b10;
      #pragma unroll
      for (int mt = 0; mt < 2; mt++) {
        const short8 af = *reinterpret_cast<const short8*>(&wtw[(mt * 16 + m16) * STR + ko]);
        acc[mt][0] = __builtin_amdgcn_mfma_f32_16x16x32_bf16(af, bA, acc[mt][0], 0, 0, 0);
        acc[mt][1] = __builtin_amdgcn_mfma_f32_16x16x32_bf16(af, bB, acc[mt][1], 0, 0, 0);
        dacc[mt]   = __builtin_amdgcn_mfma_f32_16x16x32_bf16(af, ones, dacc[mt], 0, 0, 0);
      }
    }
  }

  // epilogue: C/D layout col=lane&15, row=quad*4+reg [HW-verified]
  #pragma unroll
  for (int mt = 0; mt < 2; mt++) {
    const int rr = rb + r0 + mt * 16 + quad * 4;
    #pragma unroll
    for (int r = 0; r < 4; r++) {
      atomicAdd(&hacc[(size_t)(rr + r) * DD + m16],      acc[mt][0][r]);
      atomicAdd(&hacc[(size_t)(rr + r) * DD + 16 + m16], acc[mt][1][r]);
    }
    if (m16 == 0) {
      #pragma unroll
      for (int r = 0; r < 4; r++) atomicAdd(&den[rr + r], dacc[mt][r]);
    }
  }
}

// ---------------------------------------------------------------------------
// Layer 3: only row 0 of the attention output is needed (fp32 exact).
// ---------------------------------------------------------------------------
__global__ void k_att3(const unsigned long long* __restrict__ mask64,
                       const float* __restrict__ g3,
                       const float* __restrict__ ssrc,
                       const float* __restrict__ sdst,
                       float* __restrict__ o3,
                       float* __restrict__ den3)
{
  __shared__ float wl[256];
  const int t = threadIdx.x;
  const int jb = blockIdx.x * 256;
  const int j = jb + t;
  const unsigned long long mw = mask64[j >> 6];  // row 0 of mask
  const bool m = (mw >> (j & 63)) & 1ull;
  const float e = ssrc[0] + sdst[j];
  const float w = m ? __expf(fmaxf(e, 0.2f * e)) : 0.f;
  wl[t] = w;
  float v = w;
  #pragma unroll
  for (int s = 32; s > 0; s >>= 1) v += __shfl_xor(v, s, 64);
  if ((t & 63) == 0) atomicAdd(den3, v);
  __syncthreads();
  for (int idx = t; idx < 33 * 8; idx += 256) {
    const int d = idx % 33;
    const int oct = idx / 33;
    float s = 0.f;
    for (int jj = 0; jj < 32; jj++)
      s += wl[oct * 32 + jj] * g3[(size_t)(jb + oct * 32 + jj) * 33 + d];
    atomicAdd(&o3[d], s);
  }
}

// ---------------------------------------------------------------------------
// Final MLP on node 0 (leaky slope 0.01; layer-3 GAT output has NO ELU)
// ---------------------------------------------------------------------------
__global__ void k_mlp(const float* __restrict__ o3, const float* __restrict__ den3,
                      const float* __restrict__ Wm1, const float* __restrict__ bm1,
                      const float* __restrict__ Wm2, const float* __restrict__ bm2,
                      float* __restrict__ out)
{
  __shared__ float h0[33];
  __shared__ float hid[128];
  const int t = threadIdx.x;  // 128 threads
  if (t < 33) h0[t] = o3[t] / den3[0];
  __syncthreads();
  float a = bm1[t];
  for (int k = 0; k < 33; k++) a += h0[k] * Wm1[k * 128 + t];
  hid[t] = fmaxf(a, 0.01f * a);
  __syncthreads();
  if (t < 27) {
    float o = bm2[t];
    for (int k = 0; k < 128; k++) o += hid[k] * Wm2[k * 27 + t];
    out[t] = o;
  }
}

extern "C" void kernel_launch(void* const* d_in, const int* in_sizes, int n_in,
                              void* d_out, int out_size, void* d_ws, size_t ws_size,
                              hipStream_t stream)
{
  const float* x   = (const float*)d_in[0];
  const float* adj = (const float*)d_in[1];
  const float* W1  = (const float*)d_in[2];
  const float* a1  = (const float*)d_in[3];
  const float* W2  = (const float*)d_in[4];
  const float* a2  = (const float*)d_in[5];
  const float* W3  = (const float*)d_in[6];
  const float* a3  = (const float*)d_in[7];
  const float* Wm1 = (const float*)d_in[8];
  const float* bm1 = (const float*)d_in[9];
  const float* Wm2 = (const float*)d_in[10];
  const float* bm2 = (const float*)d_in[11];
  float* out = (float*)d_out;
  (void)in_sizes; (void)n_in; (void)out_size; (void)ws_size;

  char* ws = (char*)d_ws;
  size_t off = 0;
  auto alloc = [&](size_t bytes) -> void* {
    void* p = ws + off;
    off = (off + bytes + 255) & ~(size_t)255;
    return p;
  };
  float* g3  = (float*)alloc((size_t)NN * 33 * 4);
  float* s1s = (float*)alloc((size_t)NN * 4);
  float* s1d = (float*)alloc((size_t)NN * 4);
  float* s2s = (float*)alloc((size_t)NN * 4);
  float* s2d = (float*)alloc((size_t)NN * 4);
  float* s3s = (float*)alloc((size_t)NN * 4);
  float* s3d = (float*)alloc((size_t)NN * 4);
  char* zbase = ws + off;                     // contiguous zero-init region
  float* h1acc = (float*)alloc((size_t)NN * DD * 4);
  float* den1  = (float*)alloc((size_t)NN * 4);
  float* h2acc = (float*)alloc((size_t)NN * DD * 4);
  float* den2  = (float*)alloc((size_t)NN * 4);
  float* o3    = (float*)alloc(64 * 4);
  float* den3  = (float*)alloc(64 * 4);
  const size_t zbytes = (size_t)((ws + off) - zbase);
  unsigned long long* mask64 = (unsigned long long*)alloc((size_t)NN * WORDS * 8);
  unsigned short* g1T = (unsigned short*)alloc((size_t)DD * NN * 2);
  unsigned short* g2T = (unsigned short*)alloc((size_t)DD * NN * 2);

  hipMemsetAsync(zbase, 0, zbytes, stream);
  k_g<33, 32, false><<<NN / 128, 128, 0, stream>>>(x, nullptr, W1, a1, nullptr, g1T, s1s, s1d);
  k_att<1><<<(NN / ROWS) * JSPLIT, 256, 0, stream>>>(adj, mask64, g1T, s1s, s1d, h1acc, den1);
  k_g<32, 32, true><<<NN / 128, 128, 0, stream>>>(h1acc, den1, W2, a2, nullptr, g2T, s2s, s2d);
  k_att<2><<<(NN / ROWS) * JSPLIT, 256, 0, stream>>>(nullptr, mask64, g2T, s2s, s2d, h2acc, den2);
  k_g<32, 33, true><<<NN / 128, 128, 0, stream>>>(h2acc, den2, W3, a3, g3, nullptr, s3s, s3d);
  k_att3<<<NN / 256, 256, 0, stream>>>(mask64, g3, s3s, s3d, o3, den3);
  k_mlp<<<1, 128, 0, stream>>>(o3, den3, Wm1, bm1, Wm2, bm2, out);
}

// Round 4
// 489.069 us; speedup vs baseline: 1.0946x; 1.0946x over previous
//
#include <hip/hip_runtime.h>
#include <cstdint>
#include <cstddef>

namespace {
constexpr int NN     = 8192;
constexpr int DD     = 32;
constexpr int ROWS   = 128;          // rows per attention block (4 waves x 32)
constexpr int TJ     = 128;          // j-tile (four K=32 MFMA rounds)
constexpr int JSPLIT = 16;           // j-range splits -> 1024 blocks
constexpr int JRANGE = NN / JSPLIT;  // 512 -> 4 tiles per block
constexpr int WORDS  = NN / 64;      // 128 mask words per row
constexpr int STR2   = 136;          // wt row stride in halfwords (272 B, 16B-mult)
}

typedef __attribute__((ext_vector_type(8))) short short8;
typedef __attribute__((ext_vector_type(4))) float floatx4;

__device__ __forceinline__ unsigned short f2bf(float f) {
  unsigned int u = __float_as_uint(f);
  u += 0x7fffu + ((u >> 16) & 1u);          // RNE
  return (unsigned short)(u >> 16);
}

// ---------------------------------------------------------------------------
// k_g32: g = in @ W (DOUT=32; optionally in = ELU(acc/den)), bf16 gT out.
// 128 blocks x 256 thr; thread = (row r = t>>2, dgroup dg = t&3, 8 d's each).
// W transposed in LDS (rows padded to 36) for float4 reads; ss/sd reduced
// over the 4 dgroup lanes via shfl_xor.
// ---------------------------------------------------------------------------
template<int DIN, bool FROMACC>
__global__ void k_g32(const float* __restrict__ in,
                      const float* __restrict__ den,
                      const float* __restrict__ W,
                      const float* __restrict__ avec,
                      unsigned short* __restrict__ gT,
                      float* __restrict__ ssrc,
                      float* __restrict__ sdst)
{
  __shared__ float WsT[32 * 36];   // [d][k], padded
  __shared__ float as[64];
  const int t = threadIdx.x;  // 256
  for (int idx = t; idx < DIN * 32; idx += 256) {
    const int k = idx / 32, d = idx % 32;
    WsT[d * 36 + k] = W[idx];
  }
  if (t < 64) as[t] = avec[t];
  __syncthreads();

  const int r  = t >> 2;
  const int dg = t & 3;
  const int i  = blockIdx.x * 64 + r;

  float h[DIN];
  if (FROMACC) {
    const float dinv = 1.0f / den[i];
    #pragma unroll
    for (int k = 0; k < DIN; k++) {
      const float v = in[(size_t)i * DIN + k] * dinv;
      h[k] = v > 0.f ? v : (__expf(v) - 1.0f);      // ELU
    }
  } else {
    #pragma unroll
    for (int k = 0; k < DIN; k++) h[k] = in[(size_t)i * DIN + k];
  }

  float ss = 0.f, sd = 0.f;
  #pragma unroll
  for (int d8 = 0; d8 < 8; d8++) {
    const int d = dg * 8 + d8;
    float a = 0.f;
    #pragma unroll
    for (int kb = 0; kb < DIN / 4; kb++) {
      const float4 wv = *reinterpret_cast<const float4*>(&WsT[d * 36 + kb * 4]);
      a += h[kb * 4] * wv.x + h[kb * 4 + 1] * wv.y + h[kb * 4 + 2] * wv.z + h[kb * 4 + 3] * wv.w;
    }
    #pragma unroll
    for (int k = (DIN / 4) * 4; k < DIN; k++) a += h[k] * WsT[d * 36 + k];
    gT[(size_t)d * NN + i] = f2bf(a);
    ss += a * as[d];
    sd += a * as[32 + d];
  }
  ss += __shfl_xor(ss, 1, 64); ss += __shfl_xor(ss, 2, 64);
  sd += __shfl_xor(sd, 1, 64); sd += __shfl_xor(sd, 2, 64);
  if (dg == 0) { ssrc[i] = ss; sdst[i] = sd; }
}

// ---------------------------------------------------------------------------
// k_g (per-row form) for layer 3: fp32 g out, DOUT=33.
// ---------------------------------------------------------------------------
template<int DIN, int DOUT>
__global__ void k_g(const float* __restrict__ in,
                    const float* __restrict__ den,
                    const float* __restrict__ W,
                    const float* __restrict__ avec,
                    float* __restrict__ g,
                    float* __restrict__ ssrc,
                    float* __restrict__ sdst)
{
  __shared__ float Ws[DIN * DOUT];
  __shared__ float as[2 * DOUT];
  const int t = threadIdx.x;  // 128
  for (int idx = t; idx < DIN * DOUT; idx += 128) Ws[idx] = W[idx];
  if (t < 2 * DOUT) as[t] = avec[t];
  __syncthreads();

  const int i = blockIdx.x * 128 + t;
  float h[DIN];
  const float dinv = 1.0f / den[i];
  #pragma unroll
  for (int k = 0; k < DIN; k++) {
    const float v = in[(size_t)i * DIN + k] * dinv;
    h[k] = v > 0.f ? v : (__expf(v) - 1.0f);        // ELU
  }
  float ss = 0.f, sd = 0.f;
  #pragma unroll 4
  for (int d = 0; d < DOUT; d++) {
    float a = 0.f;
    #pragma unroll
    for (int k = 0; k < DIN; k++) a += h[k] * Ws[k * DOUT + d];
    g[(size_t)i * DOUT + d] = a;
    ss += a * as[d];
    sd += a * as[DOUT + d];
  }
  ssrc[i] = ss;
  sdst[i] = sd;
}

// ---------------------------------------------------------------------------
// Attention layer (D=32), bf16 MFMA, barrier-free, TJ=128, float2 adj loads.
// Lane L owns j = jt+2L, jt+2L+1. Mask layout per 128-j tile: 2 interleaved
// ballot words (word c bit L <-> j = jt+2L+c); layers 2/3 read the same map.
// Denominator via ones-B MFMA (identical bf16 w in num & den -> cancels).
// ---------------------------------------------------------------------------
template<int LAYER>
__global__ __launch_bounds__(256, 4)
void k_att(const float* __restrict__ adj,
           unsigned long long* __restrict__ mask64,
           const unsigned short* __restrict__ gT,
           const float* __restrict__ ssrc,
           const float* __restrict__ sdst,
           float* __restrict__ hacc,
           float* __restrict__ den)
{
  __shared__ unsigned short wt[4][32 * STR2];   // per-wave private, 34.8 KB

  const int t    = threadIdx.x;
  const int lane = t & 63;
  const int wv   = __builtin_amdgcn_readfirstlane(t >> 6);
  const int quad = lane >> 4;
  const int m16  = lane & 15;
  const int rb   = (blockIdx.x / JSPLIT) * ROWS;
  const int j0   = (blockIdx.x % JSPLIT) * JRANGE;
  const int r0   = wv * 32;                     // this wave's 32 rows
  unsigned short* wtw = wt[wv];

  floatx4 acc[2][2];
  floatx4 dacc[2];
  #pragma unroll
  for (int a = 0; a < 2; a++) {
    dacc[a] = (floatx4){0.f, 0.f, 0.f, 0.f};
    #pragma unroll
    for (int b = 0; b < 2; b++) acc[a][b] = (floatx4){0.f, 0.f, 0.f, 0.f};
  }
  short8 ones;
  #pragma unroll
  for (int k = 0; k < 8; k++) ones[k] = (short)0x3F80;  // bf16 1.0

  for (int jt = j0; jt < j0 + JRANGE; jt += TJ) {
    const float2 sd01 = *reinterpret_cast<const float2*>(&sdst[jt + 2 * lane]);

    // ---- phase A: w for 32 rows x 128 j, two batches of 16 rows ----
    #pragma unroll
    for (int hb = 0; hb < 2; hb++) {
      if constexpr (LAYER == 1) {
        float2 av[16];
        #pragma unroll
        for (int ii = 0; ii < 16; ii++)
          av[ii] = *reinterpret_cast<const float2*>(
              &adj[(size_t)(rb + r0 + hb * 16 + ii) * NN + jt + 2 * lane]);
        #pragma unroll
        for (int ii = 0; ii < 16; ii++) {
          const int il = hb * 16 + ii;
          const int iu = rb + r0 + il;
          const float sa = ssrc[iu];                       // uniform -> s_load
          const bool m0 = av[ii].x > 0.5f;
          const bool m1 = av[ii].y > 0.5f;
          const unsigned long long b0 = __ballot(m0);
          const unsigned long long b1 = __ballot(m1);
          if (lane == 0) {
            ulonglong2 bb; bb.x = b0; bb.y = b1;
            *reinterpret_cast<ulonglong2*>(&mask64[(size_t)iu * WORDS + (jt >> 6)]) = bb;
          }
          const float e0 = sa + sd01.x, e1 = sa + sd01.y;
          const float w0 = m0 ? __expf(fmaxf(e0, 0.2f * e0)) : 0.f;
          const float w1 = m1 ? __expf(fmaxf(e1, 0.2f * e1)) : 0.f;
          const unsigned int pk = (unsigned int)f2bf(w0) | ((unsigned int)f2bf(w1) << 16);
          *reinterpret_cast<unsigned int*>(&wtw[il * STR2 + 2 * lane]) = pk;
        }
      } else {
        #pragma unroll
        for (int ii = 0; ii < 16; ii++) {
          const int il = hb * 16 + ii;
          const int iu = rb + r0 + il;
          const float sa = ssrc[iu];
          const ulonglong2 mw = *reinterpret_cast<const ulonglong2*>(
              &mask64[(size_t)iu * WORDS + (jt >> 6)]);          // uniform
          const bool m0 = (mw.x >> lane) & 1ull;
          const bool m1 = (mw.y >> lane) & 1ull;
          const float e0 = sa + sd01.x, e1 = sa + sd01.y;
          const float w0 = m0 ? __expf(fmaxf(e0, 0.2f * e0)) : 0.f;
          const float w1 = m1 ? __expf(fmaxf(e1, 0.2f * e1)) : 0.f;
          const unsigned int pk = (unsigned int)f2bf(w0) | ((unsigned int)f2bf(w1) << 16);
          *reinterpret_cast<unsigned int*>(&wtw[il * STR2 + 2 * lane]) = pk;
        }
      }
    }

    // ---- phase B: 4 K=32 steps; A from own wt, B direct from gT (L1/L2) ----
    #pragma unroll
    for (int ks = 0; ks < 4; ks++) {
      const int ko = ks * 32 + quad * 8;   // halfword k-offset in tile
      const short8 bf0 = *reinterpret_cast<const short8*>(&gT[(size_t)m16 * NN + jt + ko]);
      const short8 bf1 = *reinterpret_cast<const short8*>(&gT[(size_t)(16 + m16) * NN + jt + ko]);
      #pragma unroll
      for (int mt = 0; mt < 2; mt++) {
        const short8 af = *reinterpret_cast<const short8*>(&wtw[(mt * 16 + m16) * STR2 + ko]);
        acc[mt][0] = __builtin_amdgcn_mfma_f32_16x16x32_bf16(af, bf0, acc[mt][0], 0, 0, 0);
        acc[mt][1] = __builtin_amdgcn_mfma_f32_16x16x32_bf16(af, bf1, acc[mt][1], 0, 0, 0);
        dacc[mt]   = __builtin_amdgcn_mfma_f32_16x16x32_bf16(af, ones, dacc[mt], 0, 0, 0);
      }
    }
  }

  // epilogue: C/D layout col=lane&15, row=quad*4+reg [HW-verified]
  #pragma unroll
  for (int mt = 0; mt < 2; mt++) {
    const int rr = rb + r0 + mt * 16 + quad * 4;
    #pragma unroll
    for (int r = 0; r < 4; r++) {
      atomicAdd(&hacc[(size_t)(rr + r) * DD + m16],      acc[mt][0][r]);
      atomicAdd(&hacc[(size_t)(rr + r) * DD + 16 + m16], acc[mt][1][r]);
    }
    if (m16 == 0) {
      #pragma unroll
      for (int r = 0; r < 4; r++) atomicAdd(&den[rr + r], dacc[mt][r]);
    }
  }
}

// ---------------------------------------------------------------------------
// Layer 3: only row 0 of the attention output is needed (fp32 exact).
// Mask layout: word = ((j>>7)<<1)|(j&1), bit = (j>>1)&63.
// ---------------------------------------------------------------------------
__global__ void k_att3(const unsigned long long* __restrict__ mask64,
                       const float* __restrict__ g3,
                       const float* __restrict__ ssrc,
                       const float* __restrict__ sdst,
                       float* __restrict__ o3,
                       float* __restrict__ den3)
{
  __shared__ float wl[256];
  const int t = threadIdx.x;
  const int jb = blockIdx.x * 256;
  const int j = jb + t;
  const unsigned long long mw = mask64[((j >> 7) << 1) | (j & 1)];
  const bool m = (mw >> ((j >> 1) & 63)) & 1ull;
  const float e = ssrc[0] + sdst[j];
  const float w = m ? __expf(fmaxf(e, 0.2f * e)) : 0.f;
  wl[t] = w;
  float v = w;
  #pragma unroll
  for (int s = 32; s > 0; s >>= 1) v += __shfl_xor(v, s, 64);
  if ((t & 63) == 0) atomicAdd(den3, v);
  __syncthreads();
  for (int idx = t; idx < 33 * 8; idx += 256) {
    const int d = idx % 33;
    const int oct = idx / 33;
    float s = 0.f;
    for (int jj = 0; jj < 32; jj++)
      s += wl[oct * 32 + jj] * g3[(size_t)(jb + oct * 32 + jj) * 33 + d];
    atomicAdd(&o3[d], s);
  }
}

// ---------------------------------------------------------------------------
// Final MLP on node 0 (leaky slope 0.01; layer-3 GAT output has NO ELU)
// ---------------------------------------------------------------------------
__global__ void k_mlp(const float* __restrict__ o3, const float* __restrict__ den3,
                      const float* __restrict__ Wm1, const float* __restrict__ bm1,
                      const float* __restrict__ Wm2, const float* __restrict__ bm2,
                      float* __restrict__ out)
{
  __shared__ float h0[33];
  __shared__ float hid[128];
  const int t = threadIdx.x;  // 128 threads
  if (t < 33) h0[t] = o3[t] / den3[0];
  __syncthreads();
  float a = bm1[t];
  for (int k = 0; k < 33; k++) a += h0[k] * Wm1[k * 128 + t];
  hid[t] = fmaxf(a, 0.01f * a);
  __syncthreads();
  if (t < 27) {
    float o = bm2[t];
    for (int k = 0; k < 128; k++) o += hid[k] * Wm2[k * 27 + t];
    out[t] = o;
  }
}

extern "C" void kernel_launch(void* const* d_in, const int* in_sizes, int n_in,
                              void* d_out, int out_size, void* d_ws, size_t ws_size,
                              hipStream_t stream)
{
  const float* x   = (const float*)d_in[0];
  const float* adj = (const float*)d_in[1];
  const float* W1  = (const float*)d_in[2];
  const float* a1  = (const float*)d_in[3];
  const float* W2  = (const float*)d_in[4];
  const float* a2  = (const float*)d_in[5];
  const float* W3  = (const float*)d_in[6];
  const float* a3  = (const float*)d_in[7];
  const float* Wm1 = (const float*)d_in[8];
  const float* bm1 = (const float*)d_in[9];
  const float* Wm2 = (const float*)d_in[10];
  const float* bm2 = (const float*)d_in[11];
  float* out = (float*)d_out;
  (void)in_sizes; (void)n_in; (void)out_size; (void)ws_size;

  char* ws = (char*)d_ws;
  size_t off = 0;
  auto alloc = [&](size_t bytes) -> void* {
    void* p = ws + off;
    off = (off + bytes + 255) & ~(size_t)255;
    return p;
  };
  float* g3  = (float*)alloc((size_t)NN * 33 * 4);
  float* s1s = (float*)alloc((size_t)NN * 4);
  float* s1d = (float*)alloc((size_t)NN * 4);
  float* s2s = (float*)alloc((size_t)NN * 4);
  float* s2d = (float*)alloc((size_t)NN * 4);
  float* s3s = (float*)alloc((size_t)NN * 4);
  float* s3d = (float*)alloc((size_t)NN * 4);
  char* zbase = ws + off;                     // contiguous zero-init region
  float* h1acc = (float*)alloc((size_t)NN * DD * 4);
  float* den1  = (float*)alloc((size_t)NN * 4);
  float* h2acc = (float*)alloc((size_t)NN * DD * 4);
  float* den2  = (float*)alloc((size_t)NN * 4);
  float* o3    = (float*)alloc(64 * 4);
  float* den3  = (float*)alloc(64 * 4);
  const size_t zbytes = (size_t)((ws + off) - zbase);
  unsigned long long* mask64 = (unsigned long long*)alloc((size_t)NN * WORDS * 8);
  unsigned short* g1T = (unsigned short*)alloc((size_t)DD * NN * 2);
  unsigned short* g2T = (unsigned short*)alloc((size_t)DD * NN * 2);

  hipMemsetAsync(zbase, 0, zbytes, stream);
  k_g32<33, false><<<NN / 64, 256, 0, stream>>>(x, nullptr, W1, a1, g1T, s1s, s1d);
  k_att<1><<<(NN / ROWS) * JSPLIT, 256, 0, stream>>>(adj, mask64, g1T, s1s, s1d, h1acc, den1);
  k_g32<32, true><<<NN / 64, 256, 0, stream>>>(h1acc, den1, W2, a2, g2T, s2s, s2d);
  k_att<2><<<(NN / ROWS) * JSPLIT, 256, 0, stream>>>(nullptr, mask64, g2T, s2s, s2d, h2acc, den2);
  k_g<32, 33><<<NN / 128, 128, 0, stream>>>(h2acc, den2, W3, a3, g3, s3s, s3d);
  k_att3<<<NN / 256, 256, 0, stream>>>(mask64, g3, s3s, s3d, o3, den3);
  k_mlp<<<1, 128, 0, stream>>>(o3, den3, Wm1, bm1, Wm2, bm2, out);
}